// Round 9
// baseline (454.371 us; speedup 1.0000x reference)
//
#include <hip/hip_runtime.h>
#include <cstdint>

// RingAttractorNetwork: B=2048, N_EXC=1024, N_INH=256, 10 steps.
// Round 9: offloaded noise (r8) + 128x64 GEMM blocks, 4 waves x (32x64 out,
// 2x4 frags), BK=64 -> 6 ds_read : 8 MFMA per ks (0.75KB/MFMA, -25% LDS
// traffic vs r5/r8) and half the barriers per output row. 48KB LDS, 3 blk/CU,
// 576 total blocks (all co-resident). Numerics identical (absmax 0.0078).

#define N_EXC 1024
#define N_INH 256
#define BATCH 2048
#define STEPS 10
#define MAX_POIS 32
#define NE_TOT (BATCH * N_EXC)
#define NTOT   (NE_TOT + BATCH * N_INH)
#define NZ_SLICES 16                      // noise y-slices (x16 blocks = 256)

typedef short s16x8 __attribute__((ext_vector_type(8)));
typedef float f32x4 __attribute__((ext_vector_type(4)));

typedef __attribute__((address_space(1))) const void GV;
typedef __attribute__((address_space(3))) void LV;

struct U2 { uint32_t x, y; };

__device__ __forceinline__ uint32_t rotl32(uint32_t v, int r) {
  return (v << r) | (v >> (32 - r));
}

// JAX threefry2x32 (20 rounds).
__device__ __forceinline__ U2 threefry(U2 k, uint32_t x0, uint32_t x1) {
  uint32_t ks0 = k.x, ks1 = k.y, ks2 = k.x ^ k.y ^ 0x1BD11BDAu;
  x0 += ks0; x1 += ks1;
#define TF_R4(a,b,c,d) \
  x0 += x1; x1 = rotl32(x1,a); x1 ^= x0; \
  x0 += x1; x1 = rotl32(x1,b); x1 ^= x0; \
  x0 += x1; x1 = rotl32(x1,c); x1 ^= x0; \
  x0 += x1; x1 = rotl32(x1,d); x1 ^= x0;
  TF_R4(13,15,26,6)  x0 += ks1; x1 += ks2 + 1u;
  TF_R4(17,29,16,24) x0 += ks2; x1 += ks0 + 2u;
  TF_R4(13,15,26,6)  x0 += ks0; x1 += ks1 + 3u;
  TF_R4(17,29,16,24) x0 += ks1; x1 += ks2 + 4u;
  TF_R4(13,15,26,6)  x0 += ks2; x1 += ks0 + 5u;
#undef TF_R4
  U2 r; r.x = x0; r.y = x1; return r;
}

__device__ __forceinline__ unsigned short f2b(float f) {
  uint32_t u = __float_as_uint(f);
  return (unsigned short)((u + 0x7FFFu + ((u >> 16) & 1u)) >> 16);  // RNE
}

__device__ __forceinline__ void gload16(const void* g, void* l) {
  __builtin_amdgcn_global_load_lds((GV*)g, (LV*)l, 16, 0, 0);
}

// Knuth Poisson k-count for flat elements [f0::stride) of both pools.
// Partitionable random_bits: bits = h.x ^ h.y, h = threefry(subkey_n, 0, e).
__device__ void gen_noise(int f0, int stride,
                          const U2* __restrict__ ske, const U2* __restrict__ ski,
                          float lam_e, float lam_i,
                          uint8_t* __restrict__ nze, uint8_t* __restrict__ nzi) {
  for (int f = f0; f < NTOT; f += stride) {
    bool ii = f >= NE_TOT;
    uint32_t e = ii ? (uint32_t)(f - NE_TOT) : (uint32_t)f;
    const U2* sk = ii ? ski : ske;
    float neg = ii ? -lam_i : -lam_e;
    float lp = 0.0f;
    int k = 0;
#pragma unroll 1
    for (int n = 0; n < MAX_POIS; ++n) {
      if (!(lp > neg)) break;
      k++;
      U2 h = threefry(sk[n], 0u, e);
      uint32_t bits = h.x ^ h.y;
      float u = __uint_as_float((bits >> 9) | 0x3f800000u) - 1.0f;
      lp += logf(u);
    }
    (ii ? nzi : nze)[e] = (uint8_t)(k - 1);
  }
}

// Subkey chains: key = fold_in(key(42), t), split -> (ke, ki); iterated
// fold-like splits give the per-while-iteration uniform subkeys.
__global__ void keys_kernel(U2* subk_e, U2* subk_i) {
  int tid = threadIdx.x;
  if (tid >= 2 * STEPS) return;
  int t = tid >> 1;
  bool is_i = tid & 1;
  U2 base; base.x = 0u; base.y = 42u;
  U2 folded = threefry(base, 0u, (uint32_t)t);        // fold_in
  U2 ke = threefry(folded, 0u, 0u);                   // partitionable split
  U2 ki = threefry(folded, 0u, 1u);
  U2 rng = is_i ? ki : ke;
  U2* dst = (is_i ? subk_i : subk_e) + t * MAX_POIS;
  for (int n = 0; n < MAX_POIS; ++n) {
    dst[n] = threefry(rng, 0u, 1u);                   // subkey
    rng = threefry(rng, 0u, 0u);                      // carried rng
  }
}

// Step-0 noise (once, before the loop).
__global__ __launch_bounds__(256) void noise0_kernel(
    const U2* __restrict__ subk_e, const U2* __restrict__ subk_i,
    const float* __restrict__ sc_rate_e, const float* __restrict__ sc_rate_i,
    uint8_t* __restrict__ nze, uint8_t* __restrict__ nzi) {
  int flat = blockIdx.x * 256 + threadIdx.x;
  gen_noise(flat, gridDim.x * 256, subk_e, subk_i, *sc_rate_e, *sc_rate_i, nze, nzi);
}

// W_EE ring weights -> bf16. Row-normalize (incl. diagonal) in f32, then zero diag.
__global__ __launch_bounds__(256) void wee_kernel(const float* __restrict__ sigma_p,
                                                  unsigned short* __restrict__ W) {
  int i = blockIdx.x;
  int tid = threadIdx.x;
  float sigma = *sigma_p;
  const float twopi = 6.28318530717958647692f;
  const float delta = twopi / 1023.0f;
  float ai = (float)i * delta;
  float w[4];
  float s = 0.0f;
#pragma unroll
  for (int q = 0; q < 4; ++q) {
    int j = tid + q * 256;
    float aj = (float)j * delta;
    float d = aj - ai;
    float wd = atan2f(sinf(d), cosf(d));
    float x = wd / sigma;
    float v = expf(-0.5f * x * x);
    w[q] = v;
    s += v;
  }
  __shared__ float red[256];
  red[tid] = s;
  __syncthreads();
  for (int off = 128; off > 0; off >>= 1) {
    if (tid < off) red[tid] += red[tid + off];
    __syncthreads();
  }
  float sum = red[0];
#pragma unroll
  for (int q = 0; q < 4; ++q) {
    int j = tid + q * 256;
    W[i * N_EXC + j] = (j == i) ? (unsigned short)0 : f2b(w[q] / sum);
  }
}

// Transposed/converted weights + h->bf16.
__global__ void setup_kernel(const float* __restrict__ W_EI, const float* __restrict__ W_IE,
                             const float* __restrict__ h,
                             unsigned short* __restrict__ W_EIT,   // [256][1024]
                             unsigned short* __restrict__ W_IET,   // [1024][256]
                             unsigned short* __restrict__ hb) {
  int tid = blockIdx.x * blockDim.x + threadIdx.x;
  int nt = gridDim.x * blockDim.x;
  for (int i = tid; i < BATCH * N_EXC; i += nt) hb[i] = f2b(h[i]);
  for (int i = tid; i < N_INH * N_EXC; i += nt) {
    int r = i >> 10, c = i & 1023;
    W_EIT[i] = f2b(W_EI[c * N_INH + r]);
  }
  for (int i = tid; i < N_EXC * N_INH; i += nt) {
    int r = i >> 8, c = i & 255;
    W_IET[i] = f2b(W_IE[c * N_EXC + r]);
  }
}

// Pipelined GEMM phase: A-tile 128x64, B-tile 64x64 (bf16), double-buffered,
// gload_lds-staged, XOR-swizzled (rule 21: swizzle on global SOURCE + ds_read;
// LDS dest linear). Chunk j of A (16B): row=j>>3, c8=(j&7)^(row&7); byte addr of
// logical (r,c8) = r*128 + ((c8^(r&7))<<4); `addr ^ (ks<<6)` walks the ks halves
// (lhi<4 so XOR==ADD on the slot). Loop: [sync; prefetch kt+1 -> buf^1;
// compute kt] (r5 barrier-first; prefetch drains at NEXT iteration's barrier).
// Per wave per ks: 2 A-frags + 4 B-frags (6 ds_read_b128) -> 8 MFMA.
#define PIPE_GEMM(APTR, LDA, AROW0, BPTR, LDB, BROW0, KLEN, ACC)                \
  {                                                                             \
    const int NT = (KLEN) / 64;                                                 \
    int ja[4], jb[2];                                                           \
    _Pragma("unroll") for (int p = 0; p < 4; ++p) ja[p] = p * 256 + tid;        \
    _Pragma("unroll") for (int p = 0; p < 2; ++p) jb[p] = p * 256 + tid;        \
    const unsigned short* apg[4];                                               \
    const unsigned short* bpg[2];                                               \
    _Pragma("unroll") for (int p = 0; p < 4; ++p) {                             \
      int r = ja[p] >> 3, c8 = (ja[p] & 7) ^ (r & 7);                           \
      apg[p] = (APTR) + (size_t)((AROW0) + r) * (LDA) + c8 * 8;                 \
    }                                                                           \
    _Pragma("unroll") for (int p = 0; p < 2; ++p) {                             \
      int r = jb[p] >> 3, c8 = (jb[p] & 7) ^ (r & 7);                           \
      bpg[p] = (BPTR) + (size_t)((BROW0) + r) * (LDB) + c8 * 8;                 \
    }                                                                           \
    char* lA[4]; char* lB[2];                                                   \
    _Pragma("unroll") for (int p = 0; p < 4; ++p)                               \
      lA[p] = (char*)As + p * 4096 + wave * 1024;                               \
    _Pragma("unroll") for (int p = 0; p < 2; ++p)                               \
      lB[p] = (char*)Bs + p * 4096 + wave * 1024;                               \
    _Pragma("unroll") for (int p = 0; p < 4; ++p) gload16(apg[p], lA[p]);       \
    _Pragma("unroll") for (int p = 0; p < 2; ++p) gload16(bpg[p], lB[p]);       \
    int cur = 0;                                                                \
    int ra0 = wave * 32 + l16, ra1 = ra0 + 16;                                  \
    int aA0 = (ra0 << 7) | ((lhi ^ (ra0 & 7)) << 4);                            \
    int aA1 = (ra1 << 7) | ((lhi ^ (ra1 & 7)) << 4);                            \
    int aB[4];                                                                  \
    _Pragma("unroll") for (int n = 0; n < 4; ++n) {                             \
      int rb = n * 16 + l16;                                                    \
      aB[n] = (rb << 7) | ((lhi ^ (rb & 7)) << 4);                              \
    }                                                                           \
    for (int kt = 0; kt < NT; ++kt) {                                           \
      __syncthreads();                                                          \
      if (kt + 1 < NT) {                                                        \
        int k0 = (kt + 1) * 64;                                                 \
        int nbA = (cur ^ 1) * 16384, nbB = (cur ^ 1) * 8192;                    \
        _Pragma("unroll") for (int p = 0; p < 4; ++p)                           \
          gload16(apg[p] + k0, lA[p] + nbA);                                    \
        _Pragma("unroll") for (int p = 0; p < 2; ++p)                           \
          gload16(bpg[p] + k0, lB[p] + nbB);                                    \
      }                                                                         \
      const char* ab = (const char*)As + cur * 16384;                           \
      const char* bb = (const char*)Bs + cur * 8192;                            \
      _Pragma("unroll")                                                         \
      for (int ks = 0; ks < 2; ++ks) {                                          \
        int kx = ks << 6;                                                       \
        s16x8 af0 = *(const s16x8*)(ab + (aA0 ^ kx));                           \
        s16x8 af1 = *(const s16x8*)(ab + (aA1 ^ kx));                           \
        _Pragma("unroll")                                                       \
        for (int n = 0; n < 4; ++n) {                                           \
          s16x8 bf = *(const s16x8*)(bb + (aB[n] ^ kx));                        \
          ACC[0][n] = __builtin_amdgcn_mfma_f32_16x16x32_bf16(af0, bf, ACC[0][n], 0, 0, 0); \
          ACC[1][n] = __builtin_amdgcn_mfma_f32_16x16x32_bf16(af1, bf, ACC[1][n], 0, 0, 0); \
        }                                                                       \
      }                                                                         \
      cur ^= 1;                                                                 \
    }                                                                           \
  }

// Fused step. blockIdx.y: [0,16) e-GEMM cols, [16,20) i-GEMM cols, [20,36) noise t+1.
__global__ __launch_bounds__(256) void step_kernel(
    const float* __restrict__ re_in, const unsigned short* __restrict__ reb_in,
    const float* __restrict__ ri_in, const unsigned short* __restrict__ rib_in,
    const unsigned short* __restrict__ W_EEb, const unsigned short* __restrict__ W_IET,
    const unsigned short* __restrict__ W_EIT,
    const float* __restrict__ ext,
    const float* __restrict__ sc_gee, const float* __restrict__ sc_gei,
    const float* __restrict__ sc_gie, const float* __restrict__ sc_gin,
    const float* __restrict__ sc_rate_e, const float* __restrict__ sc_rate_i,
    const uint8_t* __restrict__ nz_e_in, const uint8_t* __restrict__ nz_i_in,
    uint8_t* __restrict__ nz_e_out, uint8_t* __restrict__ nz_i_out,
    const U2* __restrict__ subk_e_next, const U2* __restrict__ subk_i_next,
    float* __restrict__ re_out, unsigned short* __restrict__ reb_out,
    float* __restrict__ ri_out, unsigned short* __restrict__ rib_out) {
  __shared__ __align__(16) short As[2 * 8192];   // 2 bufs x 128x64 bf16 (16KB each)
  __shared__ __align__(16) short Bs[2 * 4096];   // 2 bufs x  64x64 bf16 ( 8KB each)
  int tid = threadIdx.x;

  if (blockIdx.y >= 20) {                        // noise role: step t+1 k-counts
    if (nz_e_out != nullptr) {
      int flat = ((blockIdx.y - 20) * gridDim.x + blockIdx.x) * 256 + tid;
      gen_noise(flat, NZ_SLICES * 16 * 256, subk_e_next, subk_i_next,
                *sc_rate_e, *sc_rate_i, nz_e_out, nz_i_out);
    }
    return;
  }

  int lane = tid & 63;
  int wave = tid >> 6;                             // wave -> 32-row band
  int l16 = lane & 15, lhi = lane >> 4;
  int b0 = blockIdx.x * 128;
  bool is_e = blockIdx.y < 16;
  int i0 = (is_e ? blockIdx.y : (blockIdx.y - 16)) * 64;

  f32x4 acc[2][4] = {};
  f32x4 acc2[2][4] = {};

  if (is_e) {
    PIPE_GEMM(reb_in, N_EXC, b0, W_EEb, N_EXC, i0, N_EXC, acc);       // NT=16
    if (rib_in != nullptr) {
      PIPE_GEMM(rib_in, N_INH, b0, W_IET, N_INH, i0, N_INH, acc2);    // NT=4
    }
    float gee = *sc_gee, gie = *sc_gie, gin = *sc_gin, rate = *sc_rate_e;
#pragma unroll
    for (int mm = 0; mm < 2; ++mm)
#pragma unroll
      for (int nn = 0; nn < 4; ++nn)
#pragma unroll
        for (int q = 0; q < 4; ++q) {
          int row = b0 + wave * 32 + mm * 16 + lhi * 4 + q;  // C/D: row=(lane>>4)*4+reg
          int col = i0 + nn * 16 + l16;                      //      col=lane&15
          int idx = row * N_EXC + col;
          float val = gee * acc[mm][nn][q] - gie * acc2[mm][nn][q] + gin * ext[idx];
          val += (float)nz_e_in[idx] - rate;
          float ro = re_in[idx];
          float rn = ro + (0.1f * (fmaxf(val, 0.0f) - ro)) / 10.0f;
          rn = fmaxf(rn, 0.0f);
          re_out[idx] = rn;
          reb_out[idx] = f2b(rn);
        }
  } else {
    PIPE_GEMM(reb_in, N_EXC, b0, W_EIT, N_EXC, i0, N_EXC, acc);       // NT=16
    float gei = *sc_gei, rate = *sc_rate_i;
#pragma unroll
    for (int mm = 0; mm < 2; ++mm)
#pragma unroll
      for (int nn = 0; nn < 4; ++nn)
#pragma unroll
        for (int q = 0; q < 4; ++q) {
          int row = b0 + wave * 32 + mm * 16 + lhi * 4 + q;
          int col = i0 + nn * 16 + l16;
          int idx = row * N_INH + col;
          float val = gei * acc[mm][nn][q];
          val += (float)nz_i_in[idx] - rate;
          float rio = (ri_in != nullptr) ? ri_in[idx] : 0.0f;
          float rn = rio + (0.1f * (fmaxf(val, 0.0f) - rio)) / 5.0f;
          rn = fmaxf(rn, 0.0f);
          ri_out[idx] = rn;
          rib_out[idx] = f2b(rn);
        }
  }
}

extern "C" void kernel_launch(void* const* d_in, const int* in_sizes, int n_in,
                              void* d_out, int out_size, void* d_ws, size_t ws_size,
                              hipStream_t stream) {
  const float* ext    = (const float*)d_in[0];
  const float* h      = (const float*)d_in[1];
  const float* sigma  = (const float*)d_in[2];
  const float* W_EI   = (const float*)d_in[3];
  const float* W_IE   = (const float*)d_in[4];
  const float* g_ee   = (const float*)d_in[5];
  const float* g_ei   = (const float*)d_in[6];
  const float* g_ie   = (const float*)d_in[7];
  const float* g_in   = (const float*)d_in[8];
  const float* rate_e = (const float*)d_in[9];
  const float* rate_i = (const float*)d_in[10];

  char* ws = (char*)d_ws;
  unsigned short* W_EEb = (unsigned short*)ws; ws += (size_t)N_EXC * N_EXC * 2;
  unsigned short* W_EIT = (unsigned short*)ws; ws += (size_t)N_INH * N_EXC * 2;
  unsigned short* W_IET = (unsigned short*)ws; ws += (size_t)N_EXC * N_INH * 2;
  float* reA            = (float*)ws;          ws += (size_t)BATCH * N_EXC * 4;
  unsigned short* rebA  = (unsigned short*)ws; ws += (size_t)BATCH * N_EXC * 2;
  unsigned short* rebB  = (unsigned short*)ws; ws += (size_t)BATCH * N_EXC * 2;
  float* riA            = (float*)ws;          ws += (size_t)BATCH * N_INH * 4;
  float* riB            = (float*)ws;          ws += (size_t)BATCH * N_INH * 4;
  unsigned short* ribA  = (unsigned short*)ws; ws += (size_t)BATCH * N_INH * 2;
  unsigned short* ribB  = (unsigned short*)ws; ws += (size_t)BATCH * N_INH * 2;
  uint8_t* nzE0         = (uint8_t*)ws;        ws += (size_t)NE_TOT;
  uint8_t* nzE1         = (uint8_t*)ws;        ws += (size_t)NE_TOT;
  uint8_t* nzI0         = (uint8_t*)ws;        ws += (size_t)BATCH * N_INH;
  uint8_t* nzI1         = (uint8_t*)ws;        ws += (size_t)BATCH * N_INH;
  U2* subk_e            = (U2*)ws;             ws += (size_t)(STEPS + 1) * MAX_POIS * sizeof(U2);
  U2* subk_i            = (U2*)ws;             ws += (size_t)(STEPS + 1) * MAX_POIS * sizeof(U2);
  float* re_dout = (float*)d_out;

  wee_kernel<<<dim3(N_EXC), dim3(256), 0, stream>>>(sigma, W_EEb);
  setup_kernel<<<dim3(512), dim3(256), 0, stream>>>(W_EI, W_IE, h, W_EIT, W_IET, rebB);
  keys_kernel<<<dim3(1), dim3(64), 0, stream>>>(subk_e, subk_i);
  noise0_kernel<<<dim3(512), dim3(256), 0, stream>>>(subk_e, subk_i, rate_e, rate_i,
                                                     nzE0, nzI0);

  for (int t = 0; t < STEPS; ++t) {
    const float* re_in          = (t == 0) ? h : ((t & 1) ? reA : re_dout);
    float* re_out               = (t & 1) ? re_dout : reA;
    const unsigned short* rb_in = (t & 1) ? rebA : rebB;   // t=0: rebB holds bf16(h)
    unsigned short* rb_out      = (t & 1) ? rebB : rebA;
    const float* ri_in          = (t == 0) ? nullptr : ((t & 1) ? riA : riB);
    float* ri_out               = (t & 1) ? riB : riA;
    const unsigned short* ib_in = (t == 0) ? nullptr : ((t & 1) ? ribA : ribB);
    unsigned short* ib_out      = (t & 1) ? ribB : ribA;
    const uint8_t* nze_in       = (t & 1) ? nzE1 : nzE0;
    const uint8_t* nzi_in       = (t & 1) ? nzI1 : nzI0;
    uint8_t* nze_out            = (t + 1 < STEPS) ? ((t & 1) ? nzE0 : nzE1) : nullptr;
    uint8_t* nzi_out            = (t + 1 < STEPS) ? ((t & 1) ? nzI0 : nzI1) : nullptr;

    step_kernel<<<dim3(BATCH / 128, 20 + NZ_SLICES), dim3(256), 0, stream>>>(
        re_in, rb_in, ri_in, ib_in, W_EEb, W_IET, W_EIT, ext,
        g_ee, g_ei, g_ie, g_in, rate_e, rate_i,
        nze_in, nzi_in, nze_out, nzi_out,
        subk_e + (t + 1) * MAX_POIS, subk_i + (t + 1) * MAX_POIS,
        re_out, rb_out, ri_out, ib_out);
  }
}

// Round 11
// 401.219 us; speedup vs baseline: 1.1325x; 1.1325x over previous
//
#include <hip/hip_runtime.h>
#include <cstdint>

// RingAttractorNetwork: B=2048, N_EXC=1024, N_INH=256, 10 steps.
// Round 11: all-steps-fused persistent kernel with SOFTWARE grid barrier
// (device-scope fences + per-step atomic counters; no cooperative API, which
// was rejected in r10). Host-side occupancy guard: fused path only if
// >=3 blocks/CU (640 blocks all co-resident); otherwise fall back to the
// r5 10-dispatch loop (known-good, 394us). Per-step math identical to r5
// (absmax 0.0078): 64x64 tiles, BK=64, 0-conflict XOR swizzle, 2-buf
// barrier-first gload_lds pipeline, inline Poisson epilogue.

#define N_EXC 1024
#define N_INH 256
#define BATCH 2048
#define STEPS 10
#define MAX_POIS 32
#define GRID_X 32
#define GRID_Y 20
#define NBLK (GRID_X * GRID_Y)

typedef short s16x8 __attribute__((ext_vector_type(8)));
typedef float f32x4 __attribute__((ext_vector_type(4)));

typedef __attribute__((address_space(1))) const void GV;
typedef __attribute__((address_space(3))) void LV;

struct U2 { uint32_t x, y; };

__device__ __forceinline__ uint32_t rotl32(uint32_t v, int r) {
  return (v << r) | (v >> (32 - r));
}

// JAX threefry2x32 (20 rounds).
__device__ __forceinline__ U2 threefry(U2 k, uint32_t x0, uint32_t x1) {
  uint32_t ks0 = k.x, ks1 = k.y, ks2 = k.x ^ k.y ^ 0x1BD11BDAu;
  x0 += ks0; x1 += ks1;
#define TF_R4(a,b,c,d) \
  x0 += x1; x1 = rotl32(x1,a); x1 ^= x0; \
  x0 += x1; x1 = rotl32(x1,b); x1 ^= x0; \
  x0 += x1; x1 = rotl32(x1,c); x1 ^= x0; \
  x0 += x1; x1 = rotl32(x1,d); x1 ^= x0;
  TF_R4(13,15,26,6)  x0 += ks1; x1 += ks2 + 1u;
  TF_R4(17,29,16,24) x0 += ks2; x1 += ks0 + 2u;
  TF_R4(13,15,26,6)  x0 += ks0; x1 += ks1 + 3u;
  TF_R4(17,29,16,24) x0 += ks1; x1 += ks2 + 4u;
  TF_R4(13,15,26,6)  x0 += ks2; x1 += ks0 + 5u;
#undef TF_R4
  U2 r; r.x = x0; r.y = x1; return r;
}

// Knuth Poisson with partitionable random_bits: bits = h.x ^ h.y,
// h = threefry(subkey_n, 0, e). Returns (poisson - lam).
__device__ __forceinline__ float poisson_mean_sub(uint32_t e,
                                                  const U2* __restrict__ sk,
                                                  float lam) {
  float neg_lam = -lam;
  float lp = 0.0f;
  int k = 0;
#pragma unroll 1
  for (int n = 0; n < MAX_POIS; ++n) {
    if (!(lp > neg_lam)) break;
    k++;
    U2 h = threefry(sk[n], 0u, e);
    uint32_t bits = h.x ^ h.y;
    float u = __uint_as_float((bits >> 9) | 0x3f800000u) - 1.0f;
    lp += logf(u);
  }
  return (float)(k - 1) - lam;
}

__device__ __forceinline__ unsigned short f2b(float f) {
  uint32_t u = __float_as_uint(f);
  return (unsigned short)((u + 0x7FFFu + ((u >> 16) & 1u)) >> 16);  // RNE
}

__device__ __forceinline__ void gload16(const void* g, void* l) {
  __builtin_amdgcn_global_load_lds((GV*)g, (LV*)l, 16, 0, 0);
}

// Software grid barrier, one counter per step (memset to 0 each launch).
// Release fence -> device-scope arrive -> acquire-spin -> all-wave acquire fence.
__device__ __forceinline__ void grid_barrier(int* ctr) {
  __syncthreads();
  if (threadIdx.x == 0) {
    __threadfence();                                   // release: wb L2
    __hip_atomic_fetch_add(ctr, 1, __ATOMIC_ACQ_REL, __HIP_MEMORY_SCOPE_AGENT);
    while (__hip_atomic_load(ctr, __ATOMIC_ACQUIRE, __HIP_MEMORY_SCOPE_AGENT) < NBLK) {
      __builtin_amdgcn_s_sleep(8);
    }
  }
  __syncthreads();
  __threadfence();                                     // acquire in every wave
}

// Subkey chains: key = fold_in(key(42), t), split -> (ke, ki); iterated
// fold-like splits give the per-while-iteration uniform subkeys.
__global__ void keys_kernel(U2* subk_e, U2* subk_i) {
  int tid = threadIdx.x;
  if (tid >= 2 * STEPS) return;
  int t = tid >> 1;
  bool is_i = tid & 1;
  U2 base; base.x = 0u; base.y = 42u;
  U2 folded = threefry(base, 0u, (uint32_t)t);        // fold_in
  U2 ke = threefry(folded, 0u, 0u);                   // partitionable split
  U2 ki = threefry(folded, 0u, 1u);
  U2 rng = is_i ? ki : ke;
  U2* dst = (is_i ? subk_i : subk_e) + t * MAX_POIS;
  for (int n = 0; n < MAX_POIS; ++n) {
    dst[n] = threefry(rng, 0u, 1u);                   // subkey
    rng = threefry(rng, 0u, 0u);                      // carried rng
  }
}

// W_EE ring weights -> bf16. Row-normalize (incl. diagonal) in f32, then zero diag.
__global__ __launch_bounds__(256) void wee_kernel(const float* __restrict__ sigma_p,
                                                  unsigned short* __restrict__ W) {
  int i = blockIdx.x;
  int tid = threadIdx.x;
  float sigma = *sigma_p;
  const float twopi = 6.28318530717958647692f;
  const float delta = twopi / 1023.0f;
  float ai = (float)i * delta;
  float w[4];
  float s = 0.0f;
#pragma unroll
  for (int q = 0; q < 4; ++q) {
    int j = tid + q * 256;
    float aj = (float)j * delta;
    float d = aj - ai;
    float wd = atan2f(sinf(d), cosf(d));
    float x = wd / sigma;
    float v = expf(-0.5f * x * x);
    w[q] = v;
    s += v;
  }
  __shared__ float red[256];
  red[tid] = s;
  __syncthreads();
  for (int off = 128; off > 0; off >>= 1) {
    if (tid < off) red[tid] += red[tid + off];
    __syncthreads();
  }
  float sum = red[0];
#pragma unroll
  for (int q = 0; q < 4; ++q) {
    int j = tid + q * 256;
    W[i * N_EXC + j] = (j == i) ? (unsigned short)0 : f2b(w[q] / sum);
  }
}

// Transposed/converted weights + h->bf16.
__global__ void setup_kernel(const float* __restrict__ W_EI, const float* __restrict__ W_IE,
                             const float* __restrict__ h,
                             unsigned short* __restrict__ W_EIT,   // [256][1024]
                             unsigned short* __restrict__ W_IET,   // [1024][256]
                             unsigned short* __restrict__ hb) {
  int tid = blockIdx.x * blockDim.x + threadIdx.x;
  int nt = gridDim.x * blockDim.x;
  for (int i = tid; i < BATCH * N_EXC; i += nt) hb[i] = f2b(h[i]);
  for (int i = tid; i < N_INH * N_EXC; i += nt) {
    int r = i >> 10, c = i & 1023;
    W_EIT[i] = f2b(W_EI[c * N_INH + r]);
  }
  for (int i = tid; i < N_EXC * N_INH; i += nt) {
    int r = i >> 8, c = i & 255;
    W_IET[i] = f2b(W_IE[c * N_EXC + r]);
  }
}

// Pipelined 64x64-tile GEMM phase, double-buffered, gload_lds-staged, XOR-swizzled.
// LDS chunk j (16B) of a [64][64]-bf16 tile holds global (row=j>>3, col16=(j&7)^(row&7)).
// Read of logical (r,c16) -> byte (r<<7) | ((c16^(r&7))<<4). Swizzle on BOTH the
// global source and the ds_read (rule 21); 0 measured conflicts (r8). Loop:
// [__syncthreads; prefetch T(kt+1)->buf^1; compute T(kt)]. NT even.
#define PIPE_GEMM(APTR, LDA, AROW0, BPTR, LDB, BROW0, KLEN, ACC)                \
  {                                                                             \
    const int NT = (KLEN) / 64;                                                 \
    int c0 = wave * 128 + lane;                                                 \
    int c1 = c0 + 64;                                                           \
    int r0 = c0 >> 3, q0 = ((c0 & 7) ^ (r0 & 7)) << 3;                          \
    int r1 = c1 >> 3, q1 = ((c1 & 7) ^ (r1 & 7)) << 3;                          \
    const unsigned short* ap0 = (APTR) + (size_t)((AROW0) + r0) * (LDA) + q0;   \
    const unsigned short* ap1 = (APTR) + (size_t)((AROW0) + r1) * (LDA) + q1;   \
    const unsigned short* bp0 = (BPTR) + (size_t)((BROW0) + r0) * (LDB) + q0;   \
    const unsigned short* bp1 = (BPTR) + (size_t)((BROW0) + r1) * (LDB) + q1;   \
    char* la0 = (char*)As + wave * 2048;                                        \
    char* la1 = la0 + 1024;                                                     \
    char* lb0 = (char*)Bs + wave * 2048;                                        \
    char* lb1 = lb0 + 1024;                                                     \
    gload16(ap0, la0); gload16(ap1, la1);                                       \
    gload16(bp0, lb0); gload16(bp1, lb1);                                       \
    int cur = 0;                                                                \
    int raf0 = wr * 32 + l16, raf1 = raf0 + 16;                                 \
    int rbf0 = wc * 32 + l16, rbf1 = rbf0 + 16;                                 \
    int aA0 = (raf0 << 7) | ((lhi ^ (raf0 & 7)) << 4);                          \
    int aA1 = (raf1 << 7) | ((lhi ^ (raf1 & 7)) << 4);                          \
    int aB0 = (rbf0 << 7) | ((lhi ^ (rbf0 & 7)) << 4);                          \
    int aB1 = (rbf1 << 7) | ((lhi ^ (rbf1 & 7)) << 4);                          \
    for (int kt = 0; kt < NT; ++kt) {                                           \
      __syncthreads();                                                          \
      if (kt + 1 < NT) {                                                        \
        int k0 = (kt + 1) * 64;                                                 \
        int nb = (cur ^ 1) * 8192;                                              \
        gload16(ap0 + k0, la0 + nb); gload16(ap1 + k0, la1 + nb);               \
        gload16(bp0 + k0, lb0 + nb); gload16(bp1 + k0, lb1 + nb);               \
      }                                                                         \
      const char* ab = (const char*)As + cur * 8192;                            \
      const char* bb = (const char*)Bs + cur * 8192;                            \
      _Pragma("unroll")                                                         \
      for (int ks = 0; ks < 2; ++ks) {                                          \
        int kx = ks << 6;                                                       \
        s16x8 af0 = *(const s16x8*)(ab + (aA0 ^ kx));                           \
        s16x8 af1 = *(const s16x8*)(ab + (aA1 ^ kx));                           \
        s16x8 bf0 = *(const s16x8*)(bb + (aB0 ^ kx));                           \
        s16x8 bf1 = *(const s16x8*)(bb + (aB1 ^ kx));                           \
        ACC[0][0] = __builtin_amdgcn_mfma_f32_16x16x32_bf16(af0, bf0, ACC[0][0], 0, 0, 0); \
        ACC[0][1] = __builtin_amdgcn_mfma_f32_16x16x32_bf16(af0, bf1, ACC[0][1], 0, 0, 0); \
        ACC[1][0] = __builtin_amdgcn_mfma_f32_16x16x32_bf16(af1, bf0, ACC[1][0], 0, 0, 0); \
        ACC[1][1] = __builtin_amdgcn_mfma_f32_16x16x32_bf16(af1, bf1, ACC[1][1], 0, 0, 0); \
      }                                                                         \
      cur ^= 1;                                                                 \
    }                                                                           \
  }

// ---- Shared per-step body (used by both fallback kernel and fused kernel) ----
#define STEP_BODY(RE_IN, RB_IN, RI_IN, IB_IN, W_EE_, W_IET_, W_EIT_, EXT_,      \
                  GEE, GEI, GIE, GIN, RATE_E, RATE_I, SKE, SKI,                 \
                  RE_OUT, RB_OUT, RI_OUT, IB_OUT)                               \
  {                                                                             \
    f32x4 acc[2][2] = {};                                                       \
    f32x4 acc2[2][2] = {};                                                      \
    if (is_e) {                                                                 \
      PIPE_GEMM(RB_IN, N_EXC, b0, W_EE_, N_EXC, i0, N_EXC, acc);                \
      if ((IB_IN) != nullptr) {                                                 \
        PIPE_GEMM(IB_IN, N_INH, b0, W_IET_, N_INH, i0, N_INH, acc2);            \
      }                                                                         \
      _Pragma("unroll")                                                         \
      for (int mm = 0; mm < 2; ++mm)                                            \
        _Pragma("unroll")                                                       \
        for (int nn = 0; nn < 2; ++nn)                                          \
          _Pragma("unroll")                                                     \
          for (int q = 0; q < 4; ++q) {                                         \
            int row = b0 + wr * 32 + mm * 16 + lhi * 4 + q;                     \
            int col = i0 + wc * 32 + nn * 16 + l16;                             \
            int idx = row * N_EXC + col;                                        \
            float val = (GEE) * acc[mm][nn][q] - (GIE) * acc2[mm][nn][q]        \
                      + (GIN) * (EXT_)[idx];                                    \
            val += poisson_mean_sub((uint32_t)idx, SKE, RATE_E);                \
            float ro = (RE_IN)[idx];                                            \
            float rn = ro + (0.1f * (fmaxf(val, 0.0f) - ro)) / 10.0f;           \
            rn = fmaxf(rn, 0.0f);                                               \
            (RE_OUT)[idx] = rn;                                                 \
            (RB_OUT)[idx] = f2b(rn);                                            \
          }                                                                     \
    } else {                                                                    \
      PIPE_GEMM(RB_IN, N_EXC, b0, W_EIT_, N_EXC, i0, N_EXC, acc);               \
      _Pragma("unroll")                                                         \
      for (int mm = 0; mm < 2; ++mm)                                            \
        _Pragma("unroll")                                                       \
        for (int nn = 0; nn < 2; ++nn)                                          \
          _Pragma("unroll")                                                     \
          for (int q = 0; q < 4; ++q) {                                         \
            int row = b0 + wr * 32 + mm * 16 + lhi * 4 + q;                     \
            int col = i0 + wc * 32 + nn * 16 + l16;                             \
            int idx = row * N_INH + col;                                        \
            float val = (GEI) * acc[mm][nn][q];                                 \
            val += poisson_mean_sub((uint32_t)idx, SKI, RATE_I);                \
            float rio = ((RI_IN) != nullptr) ? (RI_IN)[idx] : 0.0f;             \
            float rn = rio + (0.1f * (fmaxf(val, 0.0f) - rio)) / 5.0f;          \
            rn = fmaxf(rn, 0.0f);                                               \
            (RI_OUT)[idx] = rn;                                                 \
            (IB_OUT)[idx] = f2b(rn);                                            \
          }                                                                     \
    }                                                                           \
  }

// ---------------- Fallback: one dispatch per step (r5, known-good) ----------------
__global__ __launch_bounds__(256) void step_kernel(
    const float* __restrict__ re_in, const unsigned short* __restrict__ reb_in,
    const float* __restrict__ ri_in, const unsigned short* __restrict__ rib_in,
    const unsigned short* __restrict__ W_EEb, const unsigned short* __restrict__ W_IET,
    const unsigned short* __restrict__ W_EIT,
    const float* __restrict__ ext,
    const float* __restrict__ sc_gee, const float* __restrict__ sc_gei,
    const float* __restrict__ sc_gie, const float* __restrict__ sc_gin,
    const float* __restrict__ sc_rate_e, const float* __restrict__ sc_rate_i,
    const U2* __restrict__ subk_e, const U2* __restrict__ subk_i,
    float* __restrict__ re_out, unsigned short* __restrict__ reb_out,
    float* __restrict__ ri_out, unsigned short* __restrict__ rib_out) {
  __shared__ __align__(16) short As[2 * 4096];
  __shared__ __align__(16) short Bs[2 * 4096];
  int tid = threadIdx.x;
  int lane = tid & 63;
  int wave = tid >> 6;
  int wr = wave >> 1, wc = wave & 1;
  int l16 = lane & 15, lhi = lane >> 4;
  int b0 = blockIdx.x * 64;
  bool is_e = blockIdx.y < 16;
  int i0 = (is_e ? blockIdx.y : (blockIdx.y - 16)) * 64;
  float gee = *sc_gee, gei = *sc_gei, gie = *sc_gie, gin = *sc_gin;
  float rate_e = *sc_rate_e, rate_i = *sc_rate_i;
  STEP_BODY(re_in, reb_in, ri_in, rib_in, W_EEb, W_IET, W_EIT, ext,
            gee, gei, gie, gin, rate_e, rate_i, subk_e, subk_i,
            re_out, reb_out, ri_out, rib_out)
}

// ---------------- Fused: all steps in one launch, software grid barrier ----------
struct SP {
  const float* ext; const float* h;
  const unsigned short* W_EEb; const unsigned short* W_IET; const unsigned short* W_EIT;
  const float *gee, *gei, *gie, *gin, *rate_e, *rate_i;
  const U2 *subk_e, *subk_i;
  float *reA, *reD;
  unsigned short *rebA, *rebB;
  float *riA, *riB;
  unsigned short *ribA, *ribB;
  int* bar;                              // STEPS counters, zeroed each launch
};

__global__ __launch_bounds__(256, 3) void fused_kernel(SP p) {
  __shared__ __align__(16) short As[2 * 4096];
  __shared__ __align__(16) short Bs[2 * 4096];
  int tid = threadIdx.x;
  int lane = tid & 63;
  int wave = tid >> 6;
  int wr = wave >> 1, wc = wave & 1;
  int l16 = lane & 15, lhi = lane >> 4;
  int b0 = blockIdx.x * 64;
  bool is_e = blockIdx.y < 16;
  int i0 = (is_e ? blockIdx.y : (blockIdx.y - 16)) * 64;

  float gee = *p.gee, gei = *p.gei, gie = *p.gie, gin = *p.gin;
  float rate_e = *p.rate_e, rate_i = *p.rate_i;

#pragma unroll 1
  for (int t = 0; t < STEPS; ++t) {
    const float* re_in          = (t == 0) ? p.h : ((t & 1) ? p.reA : p.reD);
    float* re_out               = (t & 1) ? p.reD : p.reA;
    const unsigned short* rb_in = (t & 1) ? p.rebA : p.rebB;
    unsigned short* rb_out      = (t & 1) ? p.rebB : p.rebA;
    const float* ri_in          = (t == 0) ? nullptr : ((t & 1) ? p.riA : p.riB);
    float* ri_out               = (t & 1) ? p.riB : p.riA;
    const unsigned short* ib_in = (t == 0) ? nullptr : ((t & 1) ? p.ribA : p.ribB);
    unsigned short* ib_out      = (t & 1) ? p.ribB : p.ribA;
    const U2* ske = p.subk_e + t * MAX_POIS;
    const U2* ski = p.subk_i + t * MAX_POIS;

    STEP_BODY(re_in, rb_in, ri_in, ib_in, p.W_EEb, p.W_IET, p.W_EIT, p.ext,
              gee, gei, gie, gin, rate_e, rate_i, ske, ski,
              re_out, rb_out, ri_out, ib_out)

    if (t + 1 < STEPS) grid_barrier(p.bar + t);
  }
}

extern "C" void kernel_launch(void* const* d_in, const int* in_sizes, int n_in,
                              void* d_out, int out_size, void* d_ws, size_t ws_size,
                              hipStream_t stream) {
  const float* ext    = (const float*)d_in[0];
  const float* h      = (const float*)d_in[1];
  const float* sigma  = (const float*)d_in[2];
  const float* W_EI   = (const float*)d_in[3];
  const float* W_IE   = (const float*)d_in[4];
  const float* g_ee   = (const float*)d_in[5];
  const float* g_ei   = (const float*)d_in[6];
  const float* g_ie   = (const float*)d_in[7];
  const float* g_in   = (const float*)d_in[8];
  const float* rate_e = (const float*)d_in[9];
  const float* rate_i = (const float*)d_in[10];

  char* ws = (char*)d_ws;
  unsigned short* W_EEb = (unsigned short*)ws; ws += (size_t)N_EXC * N_EXC * 2;
  unsigned short* W_EIT = (unsigned short*)ws; ws += (size_t)N_INH * N_EXC * 2;
  unsigned short* W_IET = (unsigned short*)ws; ws += (size_t)N_EXC * N_INH * 2;
  float* reA            = (float*)ws;          ws += (size_t)BATCH * N_EXC * 4;
  unsigned short* rebA  = (unsigned short*)ws; ws += (size_t)BATCH * N_EXC * 2;
  unsigned short* rebB  = (unsigned short*)ws; ws += (size_t)BATCH * N_EXC * 2;
  float* riA            = (float*)ws;          ws += (size_t)BATCH * N_INH * 4;
  float* riB            = (float*)ws;          ws += (size_t)BATCH * N_INH * 4;
  unsigned short* ribA  = (unsigned short*)ws; ws += (size_t)BATCH * N_INH * 2;
  unsigned short* ribB  = (unsigned short*)ws; ws += (size_t)BATCH * N_INH * 2;
  U2* subk_e            = (U2*)ws;             ws += (size_t)STEPS * MAX_POIS * sizeof(U2);
  U2* subk_i            = (U2*)ws;             ws += (size_t)STEPS * MAX_POIS * sizeof(U2);
  int* bar              = (int*)ws;            ws += (size_t)STEPS * sizeof(int);
  float* re_dout = (float*)d_out;

  hipMemsetAsync(bar, 0, STEPS * sizeof(int), stream);
  wee_kernel<<<dim3(N_EXC), dim3(256), 0, stream>>>(sigma, W_EEb);
  setup_kernel<<<dim3(512), dim3(256), 0, stream>>>(W_EI, W_IE, h, W_EIT, W_IET, rebB);
  keys_kernel<<<dim3(1), dim3(64), 0, stream>>>(subk_e, subk_i);

  // Fused path only if the HW can hold all 640 blocks co-resident (>=3/CU).
  int nb = 0;
  hipError_t oe = hipOccupancyMaxActiveBlocksPerMultiprocessor(
      &nb, (const void*)fused_kernel, 256, 0);
  bool use_fused = (oe == hipSuccess) && (nb >= 3);

  if (use_fused) {
    SP p;
    p.ext = ext; p.h = h;
    p.W_EEb = W_EEb; p.W_IET = W_IET; p.W_EIT = W_EIT;
    p.gee = g_ee; p.gei = g_ei; p.gie = g_ie; p.gin = g_in;
    p.rate_e = rate_e; p.rate_i = rate_i;
    p.subk_e = subk_e; p.subk_i = subk_i;
    p.reA = reA; p.reD = re_dout;
    p.rebA = rebA; p.rebB = rebB;
    p.riA = riA; p.riB = riB;
    p.ribA = ribA; p.ribB = ribB;
    p.bar = bar;
    fused_kernel<<<dim3(GRID_X, GRID_Y), dim3(256), 0, stream>>>(p);
  } else {
    for (int t = 0; t < STEPS; ++t) {
      const float* re_in          = (t == 0) ? h : ((t & 1) ? reA : re_dout);
      float* re_out               = (t & 1) ? re_dout : reA;
      const unsigned short* rb_in = (t & 1) ? rebA : rebB;
      unsigned short* rb_out      = (t & 1) ? rebB : rebA;
      const float* ri_in          = (t == 0) ? nullptr : ((t & 1) ? riA : riB);
      float* ri_out               = (t & 1) ? riB : riA;
      const unsigned short* ib_in = (t == 0) ? nullptr : ((t & 1) ? ribA : ribB);
      unsigned short* ib_out      = (t & 1) ? ribB : ribA;

      step_kernel<<<dim3(GRID_X, GRID_Y), dim3(256), 0, stream>>>(
          re_in, rb_in, ri_in, ib_in, W_EEb, W_IET, W_EIT, ext,
          g_ee, g_ei, g_ie, g_in, rate_e, rate_i,
          subk_e + t * MAX_POIS, subk_i + t * MAX_POIS,
          re_out, rb_out, ri_out, ib_out);
    }
  }
}

// Round 12
// 397.819 us; speedup vs baseline: 1.1422x; 1.0085x over previous
//
#include <hip/hip_runtime.h>
#include <cstdint>

// RingAttractorNetwork: B=2048, N_EXC=1024, N_INH=256, 10 steps.
// Round 12: deterministic split-K (2 halves -> 1280 GEMM blocks, 2x waves/CU)
// + separated vectorized epilogue (Poisson at full occupancy, not serialized
// behind a GEMM block). Partials combined in FIXED order (p0+p1) -> bit-
// deterministic, no atomics. PIPE_GEMM tile structure identical to r5/r11
// (64x64, BK=64, 0-conflict XOR swizzle, 2-buf barrier-first gload_lds).

#define N_EXC 1024
#define N_INH 256
#define BATCH 2048
#define STEPS 10
#define MAX_POIS 32
#define NE_TOT (BATCH * N_EXC)            // 2,097,152
#define NTOT   (NE_TOT + BATCH * N_INH)   // 2,621,440

typedef short s16x8 __attribute__((ext_vector_type(8)));
typedef float f32x4 __attribute__((ext_vector_type(4)));
typedef unsigned short u16x4 __attribute__((ext_vector_type(4)));

typedef __attribute__((address_space(1))) const void GV;
typedef __attribute__((address_space(3))) void LV;

struct U2 { uint32_t x, y; };

__device__ __forceinline__ uint32_t rotl32(uint32_t v, int r) {
  return (v << r) | (v >> (32 - r));
}

// JAX threefry2x32 (20 rounds).
__device__ __forceinline__ U2 threefry(U2 k, uint32_t x0, uint32_t x1) {
  uint32_t ks0 = k.x, ks1 = k.y, ks2 = k.x ^ k.y ^ 0x1BD11BDAu;
  x0 += ks0; x1 += ks1;
#define TF_R4(a,b,c,d) \
  x0 += x1; x1 = rotl32(x1,a); x1 ^= x0; \
  x0 += x1; x1 = rotl32(x1,b); x1 ^= x0; \
  x0 += x1; x1 = rotl32(x1,c); x1 ^= x0; \
  x0 += x1; x1 = rotl32(x1,d); x1 ^= x0;
  TF_R4(13,15,26,6)  x0 += ks1; x1 += ks2 + 1u;
  TF_R4(17,29,16,24) x0 += ks2; x1 += ks0 + 2u;
  TF_R4(13,15,26,6)  x0 += ks0; x1 += ks1 + 3u;
  TF_R4(17,29,16,24) x0 += ks1; x1 += ks2 + 4u;
  TF_R4(13,15,26,6)  x0 += ks2; x1 += ks0 + 5u;
#undef TF_R4
  U2 r; r.x = x0; r.y = x1; return r;
}

// Knuth Poisson with partitionable random_bits: bits = h.x ^ h.y,
// h = threefry(subkey_n, 0, e). Returns (poisson - lam).
__device__ __forceinline__ float poisson_mean_sub(uint32_t e,
                                                  const U2* __restrict__ sk,
                                                  float lam) {
  float neg_lam = -lam;
  float lp = 0.0f;
  int k = 0;
#pragma unroll 1
  for (int n = 0; n < MAX_POIS; ++n) {
    if (!(lp > neg_lam)) break;
    k++;
    U2 h = threefry(sk[n], 0u, e);
    uint32_t bits = h.x ^ h.y;
    float u = __uint_as_float((bits >> 9) | 0x3f800000u) - 1.0f;
    lp += logf(u);
  }
  return (float)(k - 1) - lam;
}

__device__ __forceinline__ unsigned short f2b(float f) {
  uint32_t u = __float_as_uint(f);
  return (unsigned short)((u + 0x7FFFu + ((u >> 16) & 1u)) >> 16);  // RNE
}

__device__ __forceinline__ void gload16(const void* g, void* l) {
  __builtin_amdgcn_global_load_lds((GV*)g, (LV*)l, 16, 0, 0);
}

// Subkey chains: key = fold_in(key(42), t), split -> (ke, ki); iterated
// fold-like splits give the per-while-iteration uniform subkeys.
__global__ void keys_kernel(U2* subk_e, U2* subk_i) {
  int tid = threadIdx.x;
  if (tid >= 2 * STEPS) return;
  int t = tid >> 1;
  bool is_i = tid & 1;
  U2 base; base.x = 0u; base.y = 42u;
  U2 folded = threefry(base, 0u, (uint32_t)t);        // fold_in
  U2 ke = threefry(folded, 0u, 0u);                   // partitionable split
  U2 ki = threefry(folded, 0u, 1u);
  U2 rng = is_i ? ki : ke;
  U2* dst = (is_i ? subk_i : subk_e) + t * MAX_POIS;
  for (int n = 0; n < MAX_POIS; ++n) {
    dst[n] = threefry(rng, 0u, 1u);                   // subkey
    rng = threefry(rng, 0u, 0u);                      // carried rng
  }
}

// W_EE ring weights -> bf16. Row-normalize (incl. diagonal) in f32, then zero diag.
__global__ __launch_bounds__(256) void wee_kernel(const float* __restrict__ sigma_p,
                                                  unsigned short* __restrict__ W) {
  int i = blockIdx.x;
  int tid = threadIdx.x;
  float sigma = *sigma_p;
  const float twopi = 6.28318530717958647692f;
  const float delta = twopi / 1023.0f;
  float ai = (float)i * delta;
  float w[4];
  float s = 0.0f;
#pragma unroll
  for (int q = 0; q < 4; ++q) {
    int j = tid + q * 256;
    float aj = (float)j * delta;
    float d = aj - ai;
    float wd = atan2f(sinf(d), cosf(d));
    float x = wd / sigma;
    float v = expf(-0.5f * x * x);
    w[q] = v;
    s += v;
  }
  __shared__ float red[256];
  red[tid] = s;
  __syncthreads();
  for (int off = 128; off > 0; off >>= 1) {
    if (tid < off) red[tid] += red[tid + off];
    __syncthreads();
  }
  float sum = red[0];
#pragma unroll
  for (int q = 0; q < 4; ++q) {
    int j = tid + q * 256;
    W[i * N_EXC + j] = (j == i) ? (unsigned short)0 : f2b(w[q] / sum);
  }
}

// Transposed/converted weights + h->bf16.
__global__ void setup_kernel(const float* __restrict__ W_EI, const float* __restrict__ W_IE,
                             const float* __restrict__ h,
                             unsigned short* __restrict__ W_EIT,   // [256][1024]
                             unsigned short* __restrict__ W_IET,   // [1024][256]
                             unsigned short* __restrict__ hb) {
  int tid = blockIdx.x * blockDim.x + threadIdx.x;
  int nt = gridDim.x * blockDim.x;
  for (int i = tid; i < BATCH * N_EXC; i += nt) hb[i] = f2b(h[i]);
  for (int i = tid; i < N_INH * N_EXC; i += nt) {
    int r = i >> 10, c = i & 1023;
    W_EIT[i] = f2b(W_EI[c * N_INH + r]);
  }
  for (int i = tid; i < N_EXC * N_INH; i += nt) {
    int r = i >> 8, c = i & 255;
    W_IET[i] = f2b(W_IE[c * N_EXC + r]);
  }
}

// Pipelined 64x64-tile GEMM phase, double-buffered, gload_lds-staged, XOR-swizzled.
// LDS chunk j (16B) of a [64][64]-bf16 tile holds global (row=j>>3, col16=(j&7)^(row&7)).
// Read of logical (r,c16) -> byte (r<<7) | ((c16^(r&7))<<4). Swizzle on BOTH the
// global source and the ds_read (rule 21); 0 measured conflicts (r8). Loop:
// [__syncthreads; prefetch T(kt+1)->buf^1; compute T(kt)]. NT even.
#define PIPE_GEMM(APTR, LDA, AROW0, BPTR, LDB, BROW0, KLEN, ACC)                \
  {                                                                             \
    const int NT = (KLEN) / 64;                                                 \
    int c0 = wave * 128 + lane;                                                 \
    int c1 = c0 + 64;                                                           \
    int r0 = c0 >> 3, q0 = ((c0 & 7) ^ (r0 & 7)) << 3;                          \
    int r1 = c1 >> 3, q1 = ((c1 & 7) ^ (r1 & 7)) << 3;                          \
    const unsigned short* ap0 = (APTR) + (size_t)((AROW0) + r0) * (LDA) + q0;   \
    const unsigned short* ap1 = (APTR) + (size_t)((AROW0) + r1) * (LDA) + q1;   \
    const unsigned short* bp0 = (BPTR) + (size_t)((BROW0) + r0) * (LDB) + q0;   \
    const unsigned short* bp1 = (BPTR) + (size_t)((BROW0) + r1) * (LDB) + q1;   \
    char* la0 = (char*)As + wave * 2048;                                        \
    char* la1 = la0 + 1024;                                                     \
    char* lb0 = (char*)Bs + wave * 2048;                                        \
    char* lb1 = lb0 + 1024;                                                     \
    gload16(ap0, la0); gload16(ap1, la1);                                       \
    gload16(bp0, lb0); gload16(bp1, lb1);                                       \
    int cur = 0;                                                                \
    int raf0 = wr * 32 + l16, raf1 = raf0 + 16;                                 \
    int rbf0 = wc * 32 + l16, rbf1 = rbf0 + 16;                                 \
    int aA0 = (raf0 << 7) | ((lhi ^ (raf0 & 7)) << 4);                          \
    int aA1 = (raf1 << 7) | ((lhi ^ (raf1 & 7)) << 4);                          \
    int aB0 = (rbf0 << 7) | ((lhi ^ (rbf0 & 7)) << 4);                          \
    int aB1 = (rbf1 << 7) | ((lhi ^ (rbf1 & 7)) << 4);                          \
    for (int kt = 0; kt < NT; ++kt) {                                           \
      __syncthreads();                                                          \
      if (kt + 1 < NT) {                                                        \
        int k0 = (kt + 1) * 64;                                                 \
        int nb = (cur ^ 1) * 8192;                                              \
        gload16(ap0 + k0, la0 + nb); gload16(ap1 + k0, la1 + nb);               \
        gload16(bp0 + k0, lb0 + nb); gload16(bp1 + k0, lb1 + nb);               \
      }                                                                         \
      const char* ab = (const char*)As + cur * 8192;                            \
      const char* bb = (const char*)Bs + cur * 8192;                            \
      _Pragma("unroll")                                                         \
      for (int ks = 0; ks < 2; ++ks) {                                          \
        int kx = ks << 6;                                                       \
        s16x8 af0 = *(const s16x8*)(ab + (aA0 ^ kx));                           \
        s16x8 af1 = *(const s16x8*)(ab + (aA1 ^ kx));                           \
        s16x8 bf0 = *(const s16x8*)(bb + (aB0 ^ kx));                           \
        s16x8 bf1 = *(const s16x8*)(bb + (aB1 ^ kx));                           \
        ACC[0][0] = __builtin_amdgcn_mfma_f32_16x16x32_bf16(af0, bf0, ACC[0][0], 0, 0, 0); \
        ACC[0][1] = __builtin_amdgcn_mfma_f32_16x16x32_bf16(af0, bf1, ACC[0][1], 0, 0, 0); \
        ACC[1][0] = __builtin_amdgcn_mfma_f32_16x16x32_bf16(af1, bf0, ACC[1][0], 0, 0, 0); \
        ACC[1][1] = __builtin_amdgcn_mfma_f32_16x16x32_bf16(af1, bf1, ACC[1][1], 0, 0, 0); \
      }                                                                         \
      cur ^= 1;                                                                 \
    }                                                                           \
  }

// Split-K GEMM partial kernel. Grid (32, 20, 2): x batch-block, y column role
// ([0,16) e, [16,20) i), z = K half. Stores SCALED partials:
//   e: pe_z[idx] = gee*acc_half - gie*acc2_half   (phase2 K=256 also halved)
//   i: pi_z[idx] = gei*acc_half
__global__ __launch_bounds__(256) void gemm_partial(
    const unsigned short* __restrict__ reb_in, const unsigned short* __restrict__ rib_in,
    const unsigned short* __restrict__ W_EEb, const unsigned short* __restrict__ W_IET,
    const unsigned short* __restrict__ W_EIT,
    const float* __restrict__ sc_gee, const float* __restrict__ sc_gie,
    const float* __restrict__ sc_gei,
    float* __restrict__ pe0, float* __restrict__ pe1,
    float* __restrict__ pi0, float* __restrict__ pi1) {
  __shared__ __align__(16) short As[2 * 4096];
  __shared__ __align__(16) short Bs[2 * 4096];
  int tid = threadIdx.x;
  int lane = tid & 63;
  int wave = tid >> 6;
  int wr = wave >> 1, wc = wave & 1;
  int l16 = lane & 15, lhi = lane >> 4;
  int b0 = blockIdx.x * 64;
  bool is_e = blockIdx.y < 16;
  int i0 = (is_e ? blockIdx.y : (blockIdx.y - 16)) * 64;
  int z = blockIdx.z;

  f32x4 acc[2][2] = {};
  f32x4 acc2[2][2] = {};

  if (is_e) {
    int zoff = z * 512;                                       // K half of 1024
    PIPE_GEMM(reb_in + zoff, N_EXC, b0, W_EEb + zoff, N_EXC, i0, 512, acc);   // NT=8
    if (rib_in != nullptr) {
      int zoff2 = z * 128;                                    // K half of 256
      PIPE_GEMM(rib_in + zoff2, N_INH, b0, W_IET + zoff2, N_INH, i0, 128, acc2); // NT=2
    }
    float gee = *sc_gee, gie = *sc_gie;
    float* pz = z ? pe1 : pe0;
#pragma unroll
    for (int mm = 0; mm < 2; ++mm)
#pragma unroll
      for (int nn = 0; nn < 2; ++nn)
#pragma unroll
        for (int q = 0; q < 4; ++q) {
          int row = b0 + wr * 32 + mm * 16 + lhi * 4 + q;     // C/D: row=(lane>>4)*4+reg
          int col = i0 + wc * 32 + nn * 16 + l16;             //      col=lane&15
          pz[row * N_EXC + col] = gee * acc[mm][nn][q] - gie * acc2[mm][nn][q];
        }
  } else {
    int zoff = z * 512;
    PIPE_GEMM(reb_in + zoff, N_EXC, b0, W_EIT + zoff, N_EXC, i0, 512, acc);   // NT=8
    float gei = *sc_gei;
    float* pz = z ? pi1 : pi0;
#pragma unroll
    for (int mm = 0; mm < 2; ++mm)
#pragma unroll
      for (int nn = 0; nn < 2; ++nn)
#pragma unroll
        for (int q = 0; q < 4; ++q) {
          int row = b0 + wr * 32 + mm * 16 + lhi * 4 + q;
          int col = i0 + wc * 32 + nn * 16 + l16;
          pz[row * N_INH + col] = gei * acc[mm][nn][q];
        }
  }
}

// Vectorized epilogue: p0+p1 (fixed order) + gin*ext + Poisson -> state update.
// Grid 2560x256, thread handles 4 consecutive elements (f32x4). Blocks [0,2048)
// cover the e pool exactly; [2048,2560) the i pool.
__global__ __launch_bounds__(256) void epi_kernel(
    const float* __restrict__ pe0, const float* __restrict__ pe1,
    const float* __restrict__ pi0, const float* __restrict__ pi1,
    const float* __restrict__ ext,
    const float* __restrict__ re_in, const float* __restrict__ ri_in,
    const float* __restrict__ sc_gin,
    const float* __restrict__ sc_rate_e, const float* __restrict__ sc_rate_i,
    const U2* __restrict__ subk_e, const U2* __restrict__ subk_i,
    float* __restrict__ re_out, unsigned short* __restrict__ reb_out,
    float* __restrict__ ri_out, unsigned short* __restrict__ rib_out) {
  int gtid = blockIdx.x * 256 + threadIdx.x;
  int base = gtid * 4;
  if (base < NE_TOT) {
    float gin = *sc_gin, rate = *sc_rate_e;
    f32x4 a0 = *(const f32x4*)&pe0[base];
    f32x4 a1 = *(const f32x4*)&pe1[base];
    f32x4 ex = *(const f32x4*)&ext[base];
    f32x4 ro = *(const f32x4*)&re_in[base];
    f32x4 rn;
    u16x4 rb;
#pragma unroll
    for (int j = 0; j < 4; ++j) {
      float val = a0[j] + a1[j] + gin * ex[j];
      val += poisson_mean_sub((uint32_t)(base + j), subk_e, rate);
      float r = ro[j] + (0.1f * (fmaxf(val, 0.0f) - ro[j])) / 10.0f;
      r = fmaxf(r, 0.0f);
      rn[j] = r;
      rb[j] = f2b(r);
    }
    *(f32x4*)&re_out[base] = rn;
    *(u16x4*)&reb_out[base] = rb;
  } else {
    int e0 = base - NE_TOT;
    float rate = *sc_rate_i;
    f32x4 a0 = *(const f32x4*)&pi0[e0];
    f32x4 a1 = *(const f32x4*)&pi1[e0];
    f32x4 rn;
    u16x4 rb;
#pragma unroll
    for (int j = 0; j < 4; ++j) {
      float val = a0[j] + a1[j];
      val += poisson_mean_sub((uint32_t)(e0 + j), subk_i, rate);
      float rio = (ri_in != nullptr) ? ri_in[e0 + j] : 0.0f;
      float r = rio + (0.1f * (fmaxf(val, 0.0f) - rio)) / 5.0f;
      r = fmaxf(r, 0.0f);
      rn[j] = r;
      rb[j] = f2b(r);
    }
    *(f32x4*)&ri_out[e0] = rn;
    *(u16x4*)&rib_out[e0] = rb;
  }
}

extern "C" void kernel_launch(void* const* d_in, const int* in_sizes, int n_in,
                              void* d_out, int out_size, void* d_ws, size_t ws_size,
                              hipStream_t stream) {
  const float* ext    = (const float*)d_in[0];
  const float* h      = (const float*)d_in[1];
  const float* sigma  = (const float*)d_in[2];
  const float* W_EI   = (const float*)d_in[3];
  const float* W_IE   = (const float*)d_in[4];
  const float* g_ee   = (const float*)d_in[5];
  const float* g_ei   = (const float*)d_in[6];
  const float* g_ie   = (const float*)d_in[7];
  const float* g_in   = (const float*)d_in[8];
  const float* rate_e = (const float*)d_in[9];
  const float* rate_i = (const float*)d_in[10];

  char* ws = (char*)d_ws;
  unsigned short* W_EEb = (unsigned short*)ws; ws += (size_t)N_EXC * N_EXC * 2;  // 2 MiB
  unsigned short* W_EIT = (unsigned short*)ws; ws += (size_t)N_INH * N_EXC * 2;  // 0.5
  unsigned short* W_IET = (unsigned short*)ws; ws += (size_t)N_EXC * N_INH * 2;  // 0.5
  float* reA            = (float*)ws;          ws += (size_t)BATCH * N_EXC * 4;  // 8
  unsigned short* rebA  = (unsigned short*)ws; ws += (size_t)BATCH * N_EXC * 2;  // 4
  unsigned short* rebB  = (unsigned short*)ws; ws += (size_t)BATCH * N_EXC * 2;  // 4
  float* riA            = (float*)ws;          ws += (size_t)BATCH * N_INH * 4;  // 2
  float* riB            = (float*)ws;          ws += (size_t)BATCH * N_INH * 4;  // 2
  unsigned short* ribA  = (unsigned short*)ws; ws += (size_t)BATCH * N_INH * 2;  // 1
  unsigned short* ribB  = (unsigned short*)ws; ws += (size_t)BATCH * N_INH * 2;  // 1
  float* pe0            = (float*)ws;          ws += (size_t)BATCH * N_EXC * 4;  // 8
  float* pe1            = (float*)ws;          ws += (size_t)BATCH * N_EXC * 4;  // 8
  float* pi0            = (float*)ws;          ws += (size_t)BATCH * N_INH * 4;  // 2
  float* pi1            = (float*)ws;          ws += (size_t)BATCH * N_INH * 4;  // 2
  U2* subk_e            = (U2*)ws;             ws += (size_t)STEPS * MAX_POIS * sizeof(U2);
  U2* subk_i            = (U2*)ws;             ws += (size_t)STEPS * MAX_POIS * sizeof(U2);
  float* re_dout = (float*)d_out;

  wee_kernel<<<dim3(N_EXC), dim3(256), 0, stream>>>(sigma, W_EEb);
  setup_kernel<<<dim3(512), dim3(256), 0, stream>>>(W_EI, W_IE, h, W_EIT, W_IET, rebB);
  keys_kernel<<<dim3(1), dim3(64), 0, stream>>>(subk_e, subk_i);

  for (int t = 0; t < STEPS; ++t) {
    const float* re_in          = (t == 0) ? h : ((t & 1) ? reA : re_dout);
    float* re_out               = (t & 1) ? re_dout : reA;
    const unsigned short* rb_in = (t & 1) ? rebA : rebB;   // t=0: rebB holds bf16(h)
    unsigned short* rb_out      = (t & 1) ? rebB : rebA;
    const float* ri_in          = (t == 0) ? nullptr : ((t & 1) ? riA : riB);
    float* ri_out               = (t & 1) ? riB : riA;
    const unsigned short* ib_in = (t == 0) ? nullptr : ((t & 1) ? ribA : ribB);
    unsigned short* ib_out      = (t & 1) ? ribB : ribA;

    gemm_partial<<<dim3(BATCH / 64, 20, 2), dim3(256), 0, stream>>>(
        rb_in, ib_in, W_EEb, W_IET, W_EIT, g_ee, g_ie, g_ei, pe0, pe1, pi0, pi1);

    epi_kernel<<<dim3(NTOT / 4 / 256), dim3(256), 0, stream>>>(
        pe0, pe1, pi0, pi1, ext, re_in, ri_in, g_in, rate_e, rate_i,
        subk_e + t * MAX_POIS, subk_i + t * MAX_POIS,
        re_out, rb_out, ri_out, ib_out);
  }
}